// Round 21
// baseline (411.088 us; speedup 1.0000x reference)
//
#include <hip/hip_runtime.h>
#include <hip/hip_bf16.h>

#define S 2048
#define D 180
#define H 18
#define DKH 10
#define F 720
#define V 50257
#define VP 51200   // 400 * 128 (logits N padding)
#define KP 192     // D padded to multiple of 32
#define EPS 1e-5f
#define NEGINF (-1e30f)
#define LSTR 72    // padded LDS row stride in shorts (64 data + 8 pad)

typedef __attribute__((ext_vector_type(8))) short bf16x8;
typedef __attribute__((ext_vector_type(4))) float f32x4;

// ---------------- Wo -> bf16 padded [VP][KP], 8 elems/thread ----------------
__global__ void k_wbconv(const float* __restrict__ Wo, __hip_bfloat16* __restrict__ wb) {
    int idx = blockIdx.x * 256 + threadIdx.x;
    const int total = VP * 24;               // KP/8 = 24 chunks per row
    if (idx >= total) return;
    int n = idx / 24;
    int k0 = (idx - n * 24) * 8;
    __hip_bfloat16 tmp[8];
    #pragma unroll
    for (int j = 0; j < 8; ++j) {
        int k = k0 + j;
        float v = (n < V && k < D) ? Wo[n * D + k] : 0.0f;
        tmp[j] = __float2bfloat16(v);
    }
    *(bf16x8*)((short*)wb + n * KP + k0) = *(bf16x8*)tmp;
}

// ---------------- batched weight transpose via LDS tiles ----------------
__global__ void k_transposeAll(const float* __restrict__ Wq, const float* __restrict__ Wk,
                               const float* __restrict__ Wv, const float* __restrict__ W1,
                               const float* __restrict__ W2,
                               float* __restrict__ WqT, float* __restrict__ WkT,
                               float* __restrict__ WvT, float* __restrict__ W1T,
                               float* __restrict__ W2T) {
    __shared__ float tile[32][33];
    const float* src; float* dst; int R, C;
    switch (blockIdx.y) {
        case 0: src = Wq; dst = WqT; R = D; C = D; break;
        case 1: src = Wk; dst = WkT; R = D; C = D; break;
        case 2: src = Wv; dst = WvT; R = D; C = D; break;
        case 3: src = W1; dst = W1T; R = F; C = D; break;
        default: src = W2; dst = W2T; R = D; C = F; break;
    }
    int tilesC = (C + 31) >> 5;
    int tr = (blockIdx.x / tilesC) * 32, tc = (blockIdx.x % tilesC) * 32;
    if (tr >= R) return;
    int lx = threadIdx.x & 31, ly = threadIdx.x >> 5;   // 256 threads: ly 0..7
    #pragma unroll
    for (int rr = ly; rr < 32; rr += 8) {
        int r = tr + rr, c = tc + lx;
        tile[rr][lx] = (r < R && c < C) ? src[r * C + c] : 0.0f;
    }
    __syncthreads();
    #pragma unroll
    for (int rr = ly; rr < 32; rr += 8) {
        int c = tc + rr, r = tr + lx;
        if (c < C && r < R) dst[c * R + r] = tile[lx][rr];
    }
}

// ---------------- QKV projections with FUSED embedding+pos-encoding ----------------
__global__ void k_qkv(const int* __restrict__ ids, const float* __restrict__ emb,
                      const float* __restrict__ WqT, const float* __restrict__ WkT,
                      const float* __restrict__ WvT,
                      float* __restrict__ x0, float* __restrict__ qkv) {
    const int R = 8;
    __shared__ float xs[R * D];
    int r0 = blockIdx.x * R;
    const float* WT = (blockIdx.y == 0) ? WqT : ((blockIdx.y == 1) ? WkT : WvT);
    float* out = qkv + blockIdx.y * (S * D);
    for (int idx = threadIdx.x; idx < R * D; idx += 192) {
        int r = idx / D, d = idx - r * D;
        int row = r0 + r;
        int i = d >> 1;
        float inv = exp2f(-0.14764124866166054f * (float)i);  // 10000^(-i/90)
        float ang = (float)row * inv;
        float pe = (d & 1) ? cosf(ang) : sinf(ang);
        float v = emb[(size_t)ids[row] * D + d] + pe;
        xs[idx] = v;
        if (blockIdx.y == 0) x0[(size_t)row * D + d] = v;
    }
    __syncthreads();
    int d = threadIdx.x;
    if (d < D) {
        float acc[R] = {};
        for (int k0 = 0; k0 < D; k0 += 4) {
            f32x4 xr[R];
            #pragma unroll
            for (int r = 0; r < R; ++r) xr[r] = *(const f32x4*)&xs[r * D + k0];
            #pragma unroll
            for (int j = 0; j < 4; ++j) {
                float wv = WT[(k0 + j) * D + d];
                #pragma unroll
                for (int r = 0; r < R; ++r) acc[r] += xr[r][j] * wv;
            }
        }
        #pragma unroll
        for (int r = 0; r < R; ++r) out[(r0 + r) * D + d] = acc[r];
    }
}

// ---------------- attention pass 1: per-(chunk, q-tile, head) partials ----------------
__global__ __launch_bounds__(256) void k_attn1(const float* __restrict__ qkv,
                                               float* __restrict__ part) {
    int c = blockIdx.x, qt = blockIdx.y, h = blockIdx.z;
    if (4 * c > qt) return;                  // chunk fully above diagonal
    __shared__ float Ks[256][12];
    __shared__ float Vs[256][12];
    __shared__ float cmb[4][64][13];         // stride 13: conflict-free
    int j0 = c * 256, q0 = qt * 64;
    int t = threadIdx.x;
    int lane = t & 63, w = t >> 6;
    const float* kp = qkv + S * D + h * DKH;
    const float* vp = qkv + 2 * S * D + h * DKH;
    for (int e = t; e < 256 * DKH; e += 256) {
        int jj = e / DKH, cc = e - jj * DKH;
        Ks[jj][cc] = kp[(j0 + jj) * D + cc];
        Vs[jj][cc] = vp[(j0 + jj) * D + cc];
    }
    __syncthreads();
    int qi = q0 + lane;
    float qv[DKH];
    #pragma unroll
    for (int cc = 0; cc < DKH; ++cc) qv[cc] = qkv[qi * D + h * DKH + cc];
    float m = NEGINF, l = 0.0f, acc[DKH] = {};
    const float scale = 0.31622776601683794f;  // 1/sqrt(10)
    #pragma unroll
    for (int blk = 0; blk < 8; ++blk) {
        float sv[8], tm = NEGINF;
        #pragma unroll
        for (int u = 0; u < 8; ++u) {
            int jj = w * 64 + blk * 8 + u;
            int j = j0 + jj;
            f32x4 k0 = *(const f32x4*)&Ks[jj][0];
            f32x4 k1 = *(const f32x4*)&Ks[jj][4];
            f32x4 k2 = *(const f32x4*)&Ks[jj][8];
            float s = qv[0]*k0[0] + qv[1]*k0[1] + qv[2]*k0[2] + qv[3]*k0[3]
                    + qv[4]*k1[0] + qv[5]*k1[1] + qv[6]*k1[2] + qv[7]*k1[3]
                    + qv[8]*k2[0] + qv[9]*k2[1];
            sv[u] = (j <= qi) ? s * scale : NEGINF;
            tm = fmaxf(tm, sv[u]);
        }
        float nm = fmaxf(m, tm);
        if (nm > -0.5e30f) {
            float cor = __expf(m - nm);
            l *= cor;
            #pragma unroll
            for (int cc = 0; cc < DKH; ++cc) acc[cc] *= cor;
            m = nm;
            #pragma unroll
            for (int u = 0; u < 8; ++u) {
                float p = __expf(sv[u] - m);
                int jj = w * 64 + blk * 8 + u;
                l += p;
                f32x4 v0 = *(const f32x4*)&Vs[jj][0];
                f32x4 v1 = *(const f32x4*)&Vs[jj][4];
                f32x4 v2 = *(const f32x4*)&Vs[jj][8];
                acc[0] += p * v0[0]; acc[1] += p * v0[1];
                acc[2] += p * v0[2]; acc[3] += p * v0[3];
                acc[4] += p * v1[0]; acc[5] += p * v1[1];
                acc[6] += p * v1[2]; acc[7] += p * v1[3];
                acc[8] += p * v2[0]; acc[9] += p * v2[1];
            }
        }
    }
    cmb[w][lane][0] = m;
    cmb[w][lane][1] = l;
    #pragma unroll
    for (int cc = 0; cc < DKH; ++cc) cmb[w][lane][2 + cc] = acc[cc];
    __syncthreads();
    if (t < 64) {
        float M = NEGINF;
        #pragma unroll
        for (int ww = 0; ww < 4; ++ww) M = fmaxf(M, cmb[ww][t][0]);
        float L = 0.0f, o[DKH] = {};
        #pragma unroll
        for (int ww = 0; ww < 4; ++ww) {
            float e = __expf(cmb[ww][t][0] - M);
            L += e * cmb[ww][t][1];
            #pragma unroll
            for (int cc = 0; cc < DKH; ++cc) o[cc] += e * cmb[ww][t][2 + cc];
        }
        float* pp = part + (((size_t)(h * 32 + qt) * 9 + c) * 64 + t) * 12;
        pp[0] = M; pp[1] = L;
        #pragma unroll
        for (int cc = 0; cc < DKH; ++cc) pp[2 + cc] = o[cc];
    }
}

// ---------------- attention pass 2: merge chunk partials -> ao ----------------
__global__ void k_attn2(const float* __restrict__ part, float* __restrict__ ao) {
    int qt = blockIdx.x, h = blockIdx.y;
    int q = threadIdx.x;
    int nch = qt / 4 + 1;
    float m = NEGINF, l = 0.0f, acc[DKH] = {};
    for (int c = 0; c < nch; ++c) {
        const float* pp = part + (((size_t)(h * 32 + qt) * 9 + c) * 64 + q) * 12;
        float pm = pp[0], pl = pp[1];
        float nm = fmaxf(m, pm);
        float c1 = __expf(m - nm), c2 = __expf(pm - nm);
        l = l * c1 + pl * c2;
        #pragma unroll
        for (int cc = 0; cc < DKH; ++cc)
            acc[cc] = acc[cc] * c1 + pp[2 + cc] * c2;
        m = nm;
    }
    float inv = 1.0f / l;
    float* op = ao + (size_t)(qt * 64 + q) * D + h * DKH;
    #pragma unroll
    for (int cc = 0; cc < DKH; ++cc) op[cc] = acc[cc] * inv;
}

// ---------------- wave helpers ----------------
__device__ inline float wave_sum(float v) {
    #pragma unroll
    for (int o = 32; o > 0; o >>= 1) v += __shfl_xor(v, o);
    return v;
}

// ---------------- LayerNorm 1: x1 = LN(x0 + ao)*g + b ----------------
__global__ void k_ln1(const float* __restrict__ x0, const float* __restrict__ ao,
                      const float* __restrict__ g, const float* __restrict__ b,
                      float* __restrict__ x1) {
    int row = blockIdx.x * 4 + (threadIdx.x >> 6);
    int lane = threadIdx.x & 63;
    const float* pa = x0 + row * D;
    const float* pb = ao + row * D;
    float v[3];
    int c[3];
    float sum = 0.0f;
    #pragma unroll
    for (int k = 0; k < 3; ++k) {
        c[k] = lane + 64 * k;
        v[k] = (c[k] < D) ? (pa[c[k]] + pb[c[k]]) : 0.0f;
        sum += v[k];
    }
    sum = wave_sum(sum);
    float mu = sum / (float)D;
    float ss = 0.0f;
    #pragma unroll
    for (int k = 0; k < 3; ++k) {
        float dd = (c[k] < D) ? (v[k] - mu) : 0.0f;
        ss += dd * dd;
    }
    ss = wave_sum(ss);
    float rs = rsqrtf(ss / (float)D + EPS);
    #pragma unroll
    for (int k = 0; k < 3; ++k)
        if (c[k] < D) x1[row * D + c[k]] = (v[k] - mu) * rs * g[c[k]] + b[c[k]];
}

// ---------------- FUSED FFN: xb = bf16(LN(x1 + gelu(x1@W1^T+bf1)@W2^T + bf2)) ----------------
__global__ __launch_bounds__(768) void k_ffn(const float* __restrict__ x1,
                     const float* __restrict__ W1T, const float* __restrict__ bf1,
                     const float* __restrict__ W2T, const float* __restrict__ bf2,
                     const float* __restrict__ g, const float* __restrict__ b,
                     __hip_bfloat16* __restrict__ xb) {
    const int R = 8;
    __shared__ float xs[R * D];          // 5.76 KB
    __shared__ float ys[R * F];          // 23 KB
    __shared__ float red[2][4][3][2];    // [s1|s2][group][wave-in-group][row]
    int r0 = blockIdx.x * R;
    int t = threadIdx.x;
    for (int idx = t; idx < R * D / 4; idx += 768)
        *(f32x4*)&xs[idx * 4] = *(const f32x4*)&x1[(size_t)r0 * D + idx * 4];
    __syncthreads();
    // ---- phase 1: y = gelu(x1 @ W1^T + bf1) -> LDS ----
    if (t < F) {
        float acc[R] = {};
        for (int k0 = 0; k0 < D; k0 += 4) {
            f32x4 xr[R];
            #pragma unroll
            for (int r = 0; r < R; ++r) xr[r] = *(const f32x4*)&xs[r * D + k0];
            #pragma unroll
            for (int j = 0; j < 4; ++j) {
                float wv = W1T[(k0 + j) * F + t];
                #pragma unroll
                for (int r = 0; r < R; ++r) acc[r] += xr[r][j] * wv;
            }
        }
        float bb = bf1[t];
        #pragma unroll
        for (int r = 0; r < R; ++r) {
            float vv = acc[r] + bb;
            ys[r * F + t] = 0.5f * vv * (1.0f + erff(vv * 0.7071067811865475f));
        }
    }
    __syncthreads();
    // ---- phase 2: z = x1 + y@W2^T + bf2, then LN -> bf16 ----
    int gq = t / 192;            // group 0..3
    int d = t - gq * 192;        // 0..191
    int wig = d >> 6;            // wave-in-group 0..2
    int lane = d & 63;
    int row0 = gq * 2, row1 = gq * 2 + 1;
    float v0 = 0.0f, v1 = 0.0f;
    if (d < D) {
        float a0 = 0.0f, a1 = 0.0f;
        for (int k0 = 0; k0 < F; k0 += 4) {
            f32x4 ya = *(const f32x4*)&ys[row0 * F + k0];
            f32x4 yb = *(const f32x4*)&ys[row1 * F + k0];
            #pragma unroll
            for (int j = 0; j < 4; ++j) {
                float wv = W2T[(k0 + j) * D + d];
                a0 += ya[j] * wv;
                a1 += yb[j] * wv;
            }
        }
        float bb = bf2[d];
        v0 = x1[(size_t)(r0 + row0) * D + d] + a0 + bb;
        v1 = x1[(size_t)(r0 + row1) * D + d] + a1 + bb;
    }
    {
        float s1 = wave_sum(v0), q1 = wave_sum(v0 * v0);
        float s2 = wave_sum(v1), q2 = wave_sum(v1 * v1);
        if (lane == 0) {
            red[0][gq][wig][0] = s1; red[1][gq][wig][0] = q1;
            red[0][gq][wig][1] = s2; red[1][gq][wig][1] = q2;
        }
    }
    __syncthreads();
    float sum0 = red[0][gq][0][0] + red[0][gq][1][0] + red[0][gq][2][0];
    float sq0  = red[1][gq][0][0] + red[1][gq][1][0] + red[1][gq][2][0];
    float sum1 = red[0][gq][0][1] + red[0][gq][1][1] + red[0][gq][2][1];
    float sq1  = red[1][gq][0][1] + red[1][gq][1][1] + red[1][gq][2][1];
    float mu0 = sum0 / (float)D, var0 = sq0 / (float)D - mu0 * mu0;
    float mu1 = sum1 / (float)D, var1 = sq1 / (float)D - mu1 * mu1;
    float rs0 = rsqrtf(var0 + EPS), rs1 = rsqrtf(var1 + EPS);
    float gd = (d < D) ? g[d] : 0.0f, bd = (d < D) ? b[d] : 0.0f;
    float o0 = (d < D) ? ((v0 - mu0) * rs0 * gd + bd) : 0.0f;
    float o1 = (d < D) ? ((v1 - mu1) * rs1 * gd + bd) : 0.0f;
    xb[(size_t)(r0 + row0) * KP + d] = __float2bfloat16(o0);
    xb[(size_t)(r0 + row1) * KP + d] = __float2bfloat16(o1);
}

// ---------------- logits GEMM: A-direct (L2-resident) + B-only LDS ----------------
// r19 geometry (BM=BN=128, 8 waves x 64x32, single-buffer 6-barrier schedule)
// with A fragments loaded DIRECTLY from global (xb = 786KB, L2-resident; r13-
// proven pattern, no barrier dependency). LDS = Bs only (18KB -> more blocks/CU,
// half the staged bytes and half the ds_read stream).
// grid 6400 = 16 mtiles(128) * 400 ptiles(128).
__global__ __launch_bounds__(512) void k_logits(const __hip_bfloat16* __restrict__ xbp,
                         const __hip_bfloat16* __restrict__ wbp,
                         const float* __restrict__ bo, float* __restrict__ out) {
    __shared__ short Bs[128 * LSTR];   // 18KB
    int Lb = blockIdx.x;
    int wg = (Lb & 7) * 800 + (Lb >> 3);   // bijective XCD swizzle (6400 = 8*800)
    int mblk = wg & 15;                    // fast: B-panel L2 reuse across 16 blocks
    int pblk = wg >> 4;                    // 0..399
    int m0 = mblk * 128, n0 = pblk * 128;
    int t = threadIdx.x;
    int lane = t & 63, wid = t >> 6;       // 8 waves
    int wy = wid >> 2, wx = wid & 3;       // wave tile: rows wy*64, cols wx*32
    int r16 = lane & 15, kg = lane >> 4;
    const short* xs = (const short*)xbp;
    const short* ws = (const short*)wbp;

    int lrow = lane >> 3;                  // 0..7
    int lu = lane & 7;                     // 16B unit within 128B of chunk row

    bf16x8 gb[2];
    // per chunk: wave stages 16 B rows (wid*16 + tt*8 + lrow)
    #define GLOADB(c)                                                             \
    {                                                                             \
        _Pragma("unroll")                                                         \
        for (int tt = 0; tt < 2; ++tt) {                                          \
            int row = wid * 16 + tt * 8 + lrow;                                   \
            gb[tt] = *(const bf16x8*)(ws + (size_t)(n0 + row) * KP + (c) * 64 + lu * 8); \
        }                                                                         \
    }
    #define DSWB()                                                                \
    {                                                                             \
        _Pragma("unroll")                                                         \
        for (int tt = 0; tt < 2; ++tt) {                                          \
            int row = wid * 16 + tt * 8 + lrow;                                   \
            *(bf16x8*)&Bs[row * LSTR + lu * 8] = gb[tt];                          \
        }                                                                         \
    }

    f32x4 acc[4][2] = {};
    int arowg[4], brow[2];
    #pragma unroll
    for (int mi = 0; mi < 4; ++mi) arowg[mi] = m0 + wy * 64 + mi * 16 + r16;
    #pragma unroll
    for (int ni = 0; ni < 2; ++ni) brow[ni] = wx * 32 + ni * 16 + r16;

    // A direct from global (L2-hit), B from LDS
    #define COMPUTE(c)                                                            \
    {                                                                             \
        _Pragma("unroll")                                                         \
        for (int s = 0; s < 2; ++s) {                                             \
            bf16x8 af[4], bfr[2];                                                 \
            _Pragma("unroll")                                                     \
            for (int mi = 0; mi < 4; ++mi)                                        \
                af[mi] = *(const bf16x8*)(xs + (size_t)arowg[mi] * KP             \
                                          + (c) * 64 + (s * 4 + kg) * 8);         \
            _Pragma("unroll")                                                     \
            for (int ni = 0; ni < 2; ++ni)                                        \
                bfr[ni] = *(const bf16x8*)&Bs[brow[ni] * LSTR + (s * 4 + kg) * 8];\
            _Pragma("unroll")                                                     \
            for (int mi = 0; mi < 4; ++mi)                                        \
                _Pragma("unroll")                                                 \
                for (int ni = 0; ni < 2; ++ni)                                    \
                    acc[mi][ni] = __builtin_amdgcn_mfma_f32_16x16x32_bf16(        \
                        bfr[ni], af[mi], acc[mi][ni], 0, 0, 0);                   \
        }                                                                         \
    }

    GLOADB(0)
    DSWB()
    __syncthreads();                 // Bs(chunk0) ready
    GLOADB(1)                        // chunk1 B -> regs under compute
    COMPUTE(0)
    __syncthreads();                 // all reads of chunk0 done
    DSWB()
    __syncthreads();                 // Bs(chunk1) ready
    GLOADB(2)
    COMPUTE(1)
    __syncthreads();                 // all reads of chunk1 done
    DSWB()
    __syncthreads();                 // Bs(chunk2) ready
    COMPUTE(2)

    // epilogue: lane holds out[m0+wy*64+mi*16+r16][n0+wx*32+ni*16+kg*4+j]
    #pragma unroll
    for (int mi = 0; mi < 4; ++mi) {
        int row = arowg[mi];
        float* orow = out + (size_t)row * V;
        #pragma unroll
        for (int ni = 0; ni < 2; ++ni) {
            int cn = n0 + wx * 32 + ni * 16 + kg * 4;
            f32x4 r = acc[mi][ni];
            if (cn + 3 < V) {
                r += *(const f32x4*)(bo + cn);
                orow[cn] = r[0]; orow[cn + 1] = r[1];
                orow[cn + 2] = r[2]; orow[cn + 3] = r[3];
            } else {
                #pragma unroll
                for (int j = 0; j < 4; ++j)
                    if (cn + j < V) orow[cn + j] = r[j] + bo[cn + j];
            }
        }
    }
    #undef GLOADB
    #undef DSWB
    #undef COMPUTE
}

extern "C" void kernel_launch(void* const* d_in, const int* in_sizes, int n_in,
                              void* d_out, int out_size, void* d_ws, size_t ws_size,
                              hipStream_t stream) {
    const int* ids   = (const int*)d_in[0];
    const float* emb = (const float*)d_in[1];
    const float* Wq  = (const float*)d_in[2];
    const float* Wk  = (const float*)d_in[3];
    const float* Wv  = (const float*)d_in[4];
    const float* g1  = (const float*)d_in[5];
    const float* b1  = (const float*)d_in[6];
    const float* W1  = (const float*)d_in[7];
    const float* bf1 = (const float*)d_in[8];
    const float* W2  = (const float*)d_in[9];
    const float* bf2 = (const float*)d_in[10];
    const float* g2  = (const float*)d_in[11];
    const float* b2  = (const float*)d_in[12];
    const float* Wo  = (const float*)d_in[13];
    const float* bo  = (const float*)d_in[14];
    float* out = (float*)d_out;

    char* w = (char*)d_ws;
    float* x0 = (float*)w;           w += S * D * 4;
    float* qkv = (float*)w;          w += 3 * S * D * 4;
    float* ao = (float*)w;           w += S * D * 4;
    float* x1 = (float*)w;           w += S * D * 4;
    float* WqT = (float*)w;          w += D * D * 4;
    float* WkT = (float*)w;          w += D * D * 4;
    float* WvT = (float*)w;          w += D * D * 4;
    float* W1T = (float*)w;          w += F * D * 4;
    float* W2T = (float*)w;          w += D * F * 4;
    float* part = (float*)w;         w += (size_t)H * 32 * 9 * 64 * 12 * 4;
    __hip_bfloat16* xb = (__hip_bfloat16*)w; w += S * KP * 2;
    __hip_bfloat16* wb = (__hip_bfloat16*)w; w += (size_t)VP * KP * 2;

    k_wbconv<<<dim3((VP * 24 + 255) / 256), 256, 0, stream>>>(Wo, wb);
    k_transposeAll<<<dim3(138, 5), 256, 0, stream>>>(Wq, Wk, Wv, W1, W2,
                                                     WqT, WkT, WvT, W1T, W2T);
    k_qkv<<<dim3(S / 8, 3), 192, 0, stream>>>(ids, emb, WqT, WkT, WvT, x0, qkv);
    k_attn1<<<dim3(9, 32, H), 256, 0, stream>>>(qkv, part);
    k_attn2<<<dim3(32, H), 64, 0, stream>>>(part, ao);
    k_ln1<<<dim3(S / 4), 256, 0, stream>>>(x0, ao, g1, b1, x1);
    k_ffn<<<dim3(S / 8), 768, 0, stream>>>(x1, W1T, bf1, W2T, bf2, g2, b2, xb);
    k_logits<<<dim3(6400), 512, 0, stream>>>(xb, wb, bo, out);
}

// Round 22
// 332.942 us; speedup vs baseline: 1.2347x; 1.2347x over previous
//
#include <hip/hip_runtime.h>
#include <hip/hip_bf16.h>

#define S 2048
#define D 180
#define H 18
#define DKH 10
#define F 720
#define V 50257
#define VP 51200   // 400 * 128 (logits N padding)
#define KP 192     // D padded to multiple of 32
#define EPS 1e-5f
#define NEGINF (-1e30f)
#define LSTR 72    // padded LDS row stride in shorts (64 data + 8 pad)

typedef __attribute__((ext_vector_type(8))) short bf16x8;
typedef __attribute__((ext_vector_type(4))) float f32x4;

// ---------------- Wo -> bf16 padded [VP][KP], 8 elems/thread ----------------
__global__ void k_wbconv(const float* __restrict__ Wo, __hip_bfloat16* __restrict__ wb) {
    int idx = blockIdx.x * 256 + threadIdx.x;
    const int total = VP * 24;               // KP/8 = 24 chunks per row
    if (idx >= total) return;
    int n = idx / 24;
    int k0 = (idx - n * 24) * 8;
    __hip_bfloat16 tmp[8];
    #pragma unroll
    for (int j = 0; j < 8; ++j) {
        int k = k0 + j;
        float v = (n < V && k < D) ? Wo[n * D + k] : 0.0f;
        tmp[j] = __float2bfloat16(v);
    }
    *(bf16x8*)((short*)wb + n * KP + k0) = *(bf16x8*)tmp;
}

// ---------------- batched weight transpose via LDS tiles ----------------
__global__ void k_transposeAll(const float* __restrict__ Wq, const float* __restrict__ Wk,
                               const float* __restrict__ Wv, const float* __restrict__ W1,
                               const float* __restrict__ W2,
                               float* __restrict__ WqT, float* __restrict__ WkT,
                               float* __restrict__ WvT, float* __restrict__ W1T,
                               float* __restrict__ W2T) {
    __shared__ float tile[32][33];
    const float* src; float* dst; int R, C;
    switch (blockIdx.y) {
        case 0: src = Wq; dst = WqT; R = D; C = D; break;
        case 1: src = Wk; dst = WkT; R = D; C = D; break;
        case 2: src = Wv; dst = WvT; R = D; C = D; break;
        case 3: src = W1; dst = W1T; R = F; C = D; break;
        default: src = W2; dst = W2T; R = D; C = F; break;
    }
    int tilesC = (C + 31) >> 5;
    int tr = (blockIdx.x / tilesC) * 32, tc = (blockIdx.x % tilesC) * 32;
    if (tr >= R) return;
    int lx = threadIdx.x & 31, ly = threadIdx.x >> 5;   // 256 threads: ly 0..7
    #pragma unroll
    for (int rr = ly; rr < 32; rr += 8) {
        int r = tr + rr, c = tc + lx;
        tile[rr][lx] = (r < R && c < C) ? src[r * C + c] : 0.0f;
    }
    __syncthreads();
    #pragma unroll
    for (int rr = ly; rr < 32; rr += 8) {
        int c = tc + rr, r = tr + lx;
        if (c < C && r < R) dst[c * R + r] = tile[lx][rr];
    }
}

// ---------------- QKV projections with FUSED embedding+pos-encoding ----------------
__global__ void k_qkv(const int* __restrict__ ids, const float* __restrict__ emb,
                      const float* __restrict__ WqT, const float* __restrict__ WkT,
                      const float* __restrict__ WvT,
                      float* __restrict__ x0, float* __restrict__ qkv) {
    const int R = 8;
    __shared__ float xs[R * D];
    int r0 = blockIdx.x * R;
    const float* WT = (blockIdx.y == 0) ? WqT : ((blockIdx.y == 1) ? WkT : WvT);
    float* out = qkv + blockIdx.y * (S * D);
    for (int idx = threadIdx.x; idx < R * D; idx += 192) {
        int r = idx / D, d = idx - r * D;
        int row = r0 + r;
        int i = d >> 1;
        float inv = exp2f(-0.14764124866166054f * (float)i);  // 10000^(-i/90)
        float ang = (float)row * inv;
        float pe = (d & 1) ? cosf(ang) : sinf(ang);
        float v = emb[(size_t)ids[row] * D + d] + pe;
        xs[idx] = v;
        if (blockIdx.y == 0) x0[(size_t)row * D + d] = v;
    }
    __syncthreads();
    int d = threadIdx.x;
    if (d < D) {
        float acc[R] = {};
        for (int k0 = 0; k0 < D; k0 += 4) {
            f32x4 xr[R];
            #pragma unroll
            for (int r = 0; r < R; ++r) xr[r] = *(const f32x4*)&xs[r * D + k0];
            #pragma unroll
            for (int j = 0; j < 4; ++j) {
                float wv = WT[(k0 + j) * D + d];
                #pragma unroll
                for (int r = 0; r < R; ++r) acc[r] += xr[r][j] * wv;
            }
        }
        #pragma unroll
        for (int r = 0; r < R; ++r) out[(r0 + r) * D + d] = acc[r];
    }
}

// ---------------- attention pass 1: per-(chunk, q-tile, head) partials ----------------
__global__ __launch_bounds__(256) void k_attn1(const float* __restrict__ qkv,
                                               float* __restrict__ part) {
    int c = blockIdx.x, qt = blockIdx.y, h = blockIdx.z;
    if (4 * c > qt) return;                  // chunk fully above diagonal
    __shared__ float Ks[256][12];
    __shared__ float Vs[256][12];
    __shared__ float cmb[4][64][13];         // stride 13: conflict-free
    int j0 = c * 256, q0 = qt * 64;
    int t = threadIdx.x;
    int lane = t & 63, w = t >> 6;
    const float* kp = qkv + S * D + h * DKH;
    const float* vp = qkv + 2 * S * D + h * DKH;
    for (int e = t; e < 256 * DKH; e += 256) {
        int jj = e / DKH, cc = e - jj * DKH;
        Ks[jj][cc] = kp[(j0 + jj) * D + cc];
        Vs[jj][cc] = vp[(j0 + jj) * D + cc];
    }
    __syncthreads();
    int qi = q0 + lane;
    float qv[DKH];
    #pragma unroll
    for (int cc = 0; cc < DKH; ++cc) qv[cc] = qkv[qi * D + h * DKH + cc];
    float m = NEGINF, l = 0.0f, acc[DKH] = {};
    const float scale = 0.31622776601683794f;  // 1/sqrt(10)
    // wave-level early-out: this wave's 64-key window starts beyond every
    // query of the block -> entire window masked for all lanes
    bool wave_live = (j0 + w * 64 <= q0 + 63);
    if (wave_live) {
        #pragma unroll
        for (int blk = 0; blk < 8; ++blk) {
            float sv[8], tm = NEGINF;
            #pragma unroll
            for (int u = 0; u < 8; ++u) {
                int jj = w * 64 + blk * 8 + u;
                int j = j0 + jj;
                f32x4 k0 = *(const f32x4*)&Ks[jj][0];
                f32x4 k1 = *(const f32x4*)&Ks[jj][4];
                f32x4 k2 = *(const f32x4*)&Ks[jj][8];
                float s = qv[0]*k0[0] + qv[1]*k0[1] + qv[2]*k0[2] + qv[3]*k0[3]
                        + qv[4]*k1[0] + qv[5]*k1[1] + qv[6]*k1[2] + qv[7]*k1[3]
                        + qv[8]*k2[0] + qv[9]*k2[1];
                sv[u] = (j <= qi) ? s * scale : NEGINF;
                tm = fmaxf(tm, sv[u]);
            }
            float nm = fmaxf(m, tm);
            if (nm > -0.5e30f) {
                float cor = __expf(m - nm);
                l *= cor;
                #pragma unroll
                for (int cc = 0; cc < DKH; ++cc) acc[cc] *= cor;
                m = nm;
                #pragma unroll
                for (int u = 0; u < 8; ++u) {
                    float p = __expf(sv[u] - m);
                    int jj = w * 64 + blk * 8 + u;
                    l += p;
                    f32x4 v0 = *(const f32x4*)&Vs[jj][0];
                    f32x4 v1 = *(const f32x4*)&Vs[jj][4];
                    f32x4 v2 = *(const f32x4*)&Vs[jj][8];
                    acc[0] += p * v0[0]; acc[1] += p * v0[1];
                    acc[2] += p * v0[2]; acc[3] += p * v0[3];
                    acc[4] += p * v1[0]; acc[5] += p * v1[1];
                    acc[6] += p * v1[2]; acc[7] += p * v1[3];
                    acc[8] += p * v2[0]; acc[9] += p * v2[1];
                }
            }
        }
    }
    cmb[w][lane][0] = m;
    cmb[w][lane][1] = l;
    #pragma unroll
    for (int cc = 0; cc < DKH; ++cc) cmb[w][lane][2 + cc] = acc[cc];
    __syncthreads();
    if (t < 64) {
        float M = NEGINF;
        #pragma unroll
        for (int ww = 0; ww < 4; ++ww) M = fmaxf(M, cmb[ww][t][0]);
        float L = 0.0f, o[DKH] = {};
        #pragma unroll
        for (int ww = 0; ww < 4; ++ww) {
            float e = __expf(cmb[ww][t][0] - M);
            L += e * cmb[ww][t][1];
            #pragma unroll
            for (int cc = 0; cc < DKH; ++cc) o[cc] += e * cmb[ww][t][2 + cc];
        }
        float* pp = part + (((size_t)(h * 32 + qt) * 9 + c) * 64 + t) * 12;
        pp[0] = M; pp[1] = L;
        #pragma unroll
        for (int cc = 0; cc < DKH; ++cc) pp[2 + cc] = o[cc];
    }
}

// ---------------- attention pass 2: merge chunk partials -> ao ----------------
__global__ void k_attn2(const float* __restrict__ part, float* __restrict__ ao) {
    int qt = blockIdx.x, h = blockIdx.y;
    int q = threadIdx.x;
    int nch = qt / 4 + 1;
    float m = NEGINF, l = 0.0f, acc[DKH] = {};
    for (int c = 0; c < nch; ++c) {
        const float* pp = part + (((size_t)(h * 32 + qt) * 9 + c) * 64 + q) * 12;
        float pm = pp[0], pl = pp[1];
        float nm = fmaxf(m, pm);
        float c1 = __expf(m - nm), c2 = __expf(pm - nm);
        l = l * c1 + pl * c2;
        #pragma unroll
        for (int cc = 0; cc < DKH; ++cc)
            acc[cc] = acc[cc] * c1 + pp[2 + cc] * c2;
        m = nm;
    }
    float inv = 1.0f / l;
    float* op = ao + (size_t)(qt * 64 + q) * D + h * DKH;
    #pragma unroll
    for (int cc = 0; cc < DKH; ++cc) op[cc] = acc[cc] * inv;
}

// ---------------- wave helpers ----------------
__device__ inline float wave_sum(float v) {
    #pragma unroll
    for (int o = 32; o > 0; o >>= 1) v += __shfl_xor(v, o);
    return v;
}

// ---------------- LayerNorm 1: x1 = LN(x0 + ao)*g + b ----------------
__global__ void k_ln1(const float* __restrict__ x0, const float* __restrict__ ao,
                      const float* __restrict__ g, const float* __restrict__ b,
                      float* __restrict__ x1) {
    int row = blockIdx.x * 4 + (threadIdx.x >> 6);
    int lane = threadIdx.x & 63;
    const float* pa = x0 + row * D;
    const float* pb = ao + row * D;
    float v[3];
    int c[3];
    float sum = 0.0f;
    #pragma unroll
    for (int k = 0; k < 3; ++k) {
        c[k] = lane + 64 * k;
        v[k] = (c[k] < D) ? (pa[c[k]] + pb[c[k]]) : 0.0f;
        sum += v[k];
    }
    sum = wave_sum(sum);
    float mu = sum / (float)D;
    float ss = 0.0f;
    #pragma unroll
    for (int k = 0; k < 3; ++k) {
        float dd = (c[k] < D) ? (v[k] - mu) : 0.0f;
        ss += dd * dd;
    }
    ss = wave_sum(ss);
    float rs = rsqrtf(ss / (float)D + EPS);
    #pragma unroll
    for (int k = 0; k < 3; ++k)
        if (c[k] < D) x1[row * D + c[k]] = (v[k] - mu) * rs * g[c[k]] + b[c[k]];
}

// ---------------- FUSED FFN: xb = bf16(LN(x1 + gelu(x1@W1^T+bf1)@W2^T + bf2)) ----------------
__global__ __launch_bounds__(768) void k_ffn(const float* __restrict__ x1,
                     const float* __restrict__ W1T, const float* __restrict__ bf1,
                     const float* __restrict__ W2T, const float* __restrict__ bf2,
                     const float* __restrict__ g, const float* __restrict__ b,
                     __hip_bfloat16* __restrict__ xb) {
    const int R = 8;
    __shared__ float xs[R * D];          // 5.76 KB
    __shared__ float ys[R * F];          // 23 KB
    __shared__ float red[2][4][3][2];    // [s1|s2][group][wave-in-group][row]
    int r0 = blockIdx.x * R;
    int t = threadIdx.x;
    for (int idx = t; idx < R * D / 4; idx += 768)
        *(f32x4*)&xs[idx * 4] = *(const f32x4*)&x1[(size_t)r0 * D + idx * 4];
    __syncthreads();
    // ---- phase 1: y = gelu(x1 @ W1^T + bf1) -> LDS ----
    if (t < F) {
        float acc[R] = {};
        for (int k0 = 0; k0 < D; k0 += 4) {
            f32x4 xr[R];
            #pragma unroll
            for (int r = 0; r < R; ++r) xr[r] = *(const f32x4*)&xs[r * D + k0];
            #pragma unroll
            for (int j = 0; j < 4; ++j) {
                float wv = W1T[(k0 + j) * F + t];
                #pragma unroll
                for (int r = 0; r < R; ++r) acc[r] += xr[r][j] * wv;
            }
        }
        float bb = bf1[t];
        #pragma unroll
        for (int r = 0; r < R; ++r) {
            float vv = acc[r] + bb;
            ys[r * F + t] = 0.5f * vv * (1.0f + erff(vv * 0.7071067811865475f));
        }
    }
    __syncthreads();
    // ---- phase 2: z = x1 + y@W2^T + bf2, then LN -> bf16 ----
    int gq = t / 192;            // group 0..3
    int d = t - gq * 192;        // 0..191
    int wig = d >> 6;            // wave-in-group 0..2
    int lane = d & 63;
    int row0 = gq * 2, row1 = gq * 2 + 1;
    float v0 = 0.0f, v1 = 0.0f;
    if (d < D) {
        float a0 = 0.0f, a1 = 0.0f;
        for (int k0 = 0; k0 < F; k0 += 4) {
            f32x4 ya = *(const f32x4*)&ys[row0 * F + k0];
            f32x4 yb = *(const f32x4*)&ys[row1 * F + k0];
            #pragma unroll
            for (int j = 0; j < 4; ++j) {
                float wv = W2T[(k0 + j) * D + d];
                a0 += ya[j] * wv;
                a1 += yb[j] * wv;
            }
        }
        float bb = bf2[d];
        v0 = x1[(size_t)(r0 + row0) * D + d] + a0 + bb;
        v1 = x1[(size_t)(r0 + row1) * D + d] + a1 + bb;
    }
    {
        float s1 = wave_sum(v0), q1 = wave_sum(v0 * v0);
        float s2 = wave_sum(v1), q2 = wave_sum(v1 * v1);
        if (lane == 0) {
            red[0][gq][wig][0] = s1; red[1][gq][wig][0] = q1;
            red[0][gq][wig][1] = s2; red[1][gq][wig][1] = q2;
        }
    }
    __syncthreads();
    float sum0 = red[0][gq][0][0] + red[0][gq][1][0] + red[0][gq][2][0];
    float sq0  = red[1][gq][0][0] + red[1][gq][1][0] + red[1][gq][2][0];
    float sum1 = red[0][gq][0][1] + red[0][gq][1][1] + red[0][gq][2][1];
    float sq1  = red[1][gq][0][1] + red[1][gq][1][1] + red[1][gq][2][1];
    float mu0 = sum0 / (float)D, var0 = sq0 / (float)D - mu0 * mu0;
    float mu1 = sum1 / (float)D, var1 = sq1 / (float)D - mu1 * mu1;
    float rs0 = rsqrtf(var0 + EPS), rs1 = rsqrtf(var1 + EPS);
    float gd = (d < D) ? g[d] : 0.0f, bd = (d < D) ? b[d] : 0.0f;
    float o0 = (d < D) ? ((v0 - mu0) * rs0 * gd + bd) : 0.0f;
    float o1 = (d < D) ? ((v1 - mu1) * rs1 * gd + bd) : 0.0f;
    xb[(size_t)(r0 + row0) * KP + d] = __float2bfloat16(o0);
    xb[(size_t)(r0 + row1) * KP + d] = __float2bfloat16(o1);
}

// ---------------- logits GEMM: r19-exact (best measured: ~165us) ----------------
// BM=BN=128, BK=64 x 3 chunks, 512 threads = 8 waves, per-wave 64x32 (acc[4][2]).
// 4 blocks/CU x 8 waves = 32 waves/CU. Reg-staged linear padded LDS (LSTR=72).
// grid 6400 = 16 mtiles(128) * 400 ptiles(128).
__global__ __launch_bounds__(512) void k_logits(const __hip_bfloat16* __restrict__ xbp,
                         const __hip_bfloat16* __restrict__ wbp,
                         const float* __restrict__ bo, float* __restrict__ out) {
    __shared__ short As[128 * LSTR];   // 18KB
    __shared__ short Bs[128 * LSTR];   // 18KB
    int Lb = blockIdx.x;
    int wg = (Lb & 7) * 800 + (Lb >> 3);   // bijective XCD swizzle (6400 = 8*800)
    int mblk = wg & 15;                    // fast: wb-slice L2 reuse across 16 blocks
    int pblk = wg >> 4;                    // 0..399
    int m0 = mblk * 128, n0 = pblk * 128;
    int t = threadIdx.x;
    int lane = t & 63, wid = t >> 6;       // 8 waves
    int wy = wid >> 2, wx = wid & 3;       // wave tile: rows wy*64.., cols wx*32..
    int r16 = lane & 15, kg = lane >> 4;
    const short* xs = (const short*)xbp;
    const short* ws = (const short*)wbp;

    int lrow = lane >> 3;                  // 0..7
    int lu = lane & 7;                     // 16B unit within 128B of chunk row

    bf16x8 ga[2], gb[2];
    #define GLOAD(c)                                                              \
    {                                                                             \
        _Pragma("unroll")                                                         \
        for (int tt = 0; tt < 2; ++tt) {                                          \
            int row = wid * 16 + tt * 8 + lrow;                                   \
            ga[tt] = *(const bf16x8*)(xs + (size_t)(m0 + row) * KP + (c) * 64 + lu * 8); \
            gb[tt] = *(const bf16x8*)(ws + (size_t)(n0 + row) * KP + (c) * 64 + lu * 8); \
        }                                                                         \
    }
    #define DSW()                                                                 \
    {                                                                             \
        _Pragma("unroll")                                                         \
        for (int tt = 0; tt < 2; ++tt) {                                          \
            int row = wid * 16 + tt * 8 + lrow;                                   \
            *(bf16x8*)&As[row * LSTR + lu * 8] = ga[tt];                          \
            *(bf16x8*)&Bs[row * LSTR + lu * 8] = gb[tt];                          \
        }                                                                         \
    }

    f32x4 acc[4][2] = {};
    int arow[4], brow[2];
    #pragma unroll
    for (int mi = 0; mi < 4; ++mi) arow[mi] = wy * 64 + mi * 16 + r16;
    #pragma unroll
    for (int ni = 0; ni < 2; ++ni) brow[ni] = wx * 32 + ni * 16 + r16;

    #define COMPUTE()                                                             \
    {                                                                             \
        _Pragma("unroll")                                                         \
        for (int s = 0; s < 2; ++s) {                                             \
            bf16x8 af[4], bfr[2];                                                 \
            _Pragma("unroll")                                                     \
            for (int mi = 0; mi < 4; ++mi)                                        \
                af[mi] = *(const bf16x8*)&As[arow[mi] * LSTR + (s * 4 + kg) * 8]; \
            _Pragma("unroll")                                                     \
            for (int ni = 0; ni < 2; ++ni)                                        \
                bfr[ni] = *(const bf16x8*)&Bs[brow[ni] * LSTR + (s * 4 + kg) * 8];\
            _Pragma("unroll")                                                     \
            for (int mi = 0; mi < 4; ++mi)                                        \
                _Pragma("unroll")                                                 \
                for (int ni = 0; ni < 2; ++ni)                                    \
                    acc[mi][ni] = __builtin_amdgcn_mfma_f32_16x16x32_bf16(        \
                        bfr[ni], af[mi], acc[mi][ni], 0, 0, 0);                   \
        }                                                                         \
    }

    GLOAD(0)
    DSW()
    __syncthreads();                 // tile(chunk0) ready
    GLOAD(1)                         // chunk1 -> regs under compute
    COMPUTE()
    __syncthreads();                 // all reads of chunk0 done
    DSW()
    __syncthreads();                 // tile(chunk1) ready
    GLOAD(2)
    COMPUTE()
    __syncthreads();                 // all reads of chunk1 done
    DSW()
    __syncthreads();                 // tile(chunk2) ready
    COMPUTE()

    // epilogue: lane holds out[m0+wy*64+mi*16+r16][n0+wx*32+ni*16+kg*4+j]
    #pragma unroll
    for (int mi = 0; mi < 4; ++mi) {
        int row = m0 + wy * 64 + mi * 16 + r16;
        float* orow = out + (size_t)row * V;
        #pragma unroll
        for (int ni = 0; ni < 2; ++ni) {
            int cn = n0 + wx * 32 + ni * 16 + kg * 4;
            f32x4 r = acc[mi][ni];
            if (cn + 3 < V) {
                r += *(const f32x4*)(bo + cn);
                orow[cn] = r[0]; orow[cn + 1] = r[1];
                orow[cn + 2] = r[2]; orow[cn + 3] = r[3];
            } else {
                #pragma unroll
                for (int j = 0; j < 4; ++j)
                    if (cn + j < V) orow[cn + j] = r[j] + bo[cn + j];
            }
        }
    }
    #undef GLOAD
    #undef DSW
    #undef COMPUTE
}

extern "C" void kernel_launch(void* const* d_in, const int* in_sizes, int n_in,
                              void* d_out, int out_size, void* d_ws, size_t ws_size,
                              hipStream_t stream) {
    const int* ids   = (const int*)d_in[0];
    const float* emb = (const float*)d_in[1];
    const float* Wq  = (const float*)d_in[2];
    const float* Wk  = (const float*)d_in[3];
    const float* Wv  = (const float*)d_in[4];
    const float* g1  = (const float*)d_in[5];
    const float* b1  = (const float*)d_in[6];
    const float* W1  = (const float*)d_in[7];
    const float* bf1 = (const float*)d_in[8];
    const float* W2  = (const float*)d_in[9];
    const float* bf2 = (const float*)d_in[10];
    const float* g2  = (const float*)d_in[11];
    const float* b2  = (const float*)d_in[12];
    const float* Wo  = (const float*)d_in[13];
    const float* bo  = (const float*)d_in[14];
    float* out = (float*)d_out;

    char* w = (char*)d_ws;
    float* x0 = (float*)w;           w += S * D * 4;
    float* qkv = (float*)w;          w += 3 * S * D * 4;
    float* ao = (float*)w;           w += S * D * 4;
    float* x1 = (float*)w;           w += S * D * 4;
    float* WqT = (float*)w;          w += D * D * 4;
    float* WkT = (float*)w;          w += D * D * 4;
    float* WvT = (float*)w;          w += D * D * 4;
    float* W1T = (float*)w;          w += F * D * 4;
    float* W2T = (float*)w;          w += D * F * 4;
    float* part = (float*)w;         w += (size_t)H * 32 * 9 * 64 * 12 * 4;
    __hip_bfloat16* xb = (__hip_bfloat16*)w; w += S * KP * 2;
    __hip_bfloat16* wb = (__hip_bfloat16*)w; w += (size_t)VP * KP * 2;

    k_wbconv<<<dim3((VP * 24 + 255) / 256), 256, 0, stream>>>(Wo, wb);
    k_transposeAll<<<dim3(138, 5), 256, 0, stream>>>(Wq, Wk, Wv, W1, W2,
                                                     WqT, WkT, WvT, W1T, W2T);
    k_qkv<<<dim3(S / 8, 3), 192, 0, stream>>>(ids, emb, WqT, WkT, WvT, x0, qkv);
    k_attn1<<<dim3(9, 32, H), 256, 0, stream>>>(qkv, part);
    k_attn2<<<dim3(32, H), 64, 0, stream>>>(part, ao);
    k_ln1<<<dim3(S / 4), 256, 0, stream>>>(x0, ao, g1, b1, x1);
    k_ffn<<<dim3(S / 8), 768, 0, stream>>>(x1, W1T, bf1, W2T, bf2, g2, b2, xb);
    k_logits<<<dim3(6400), 512, 0, stream>>>(xb, wb, bo, out);
}